// Round 1
// baseline (3987.897 us; speedup 1.0000x reference)
//
#include <hip/hip_runtime.h>
#include <stdint.h>

// GreatNet: agent/context edge MLP.
// Decomposition:
//   k_ctx:        CtxP[j]  = ctx[j] @ W1c^T                       (bf16, ws)
//   k_agent_pre:  QW[i]    = relu(gn(agts[i]@q_w^T)) @ W1q^T      (bf16, ws)
//                 A0[i]    = agts[i] @ agt_w^T                    (f32, d_out)
//   k_edge:       per edge: d1=relu(d0@w1^T+b1); d=relu(gn(d1@W2^T));
//                 s = d@W1d^T + QW[hi] + CtxP[wi]; c1=relu(gn(s));
//                 c = c1@Wc2^T;  atomicAdd(A0[hi], c)
//   k_post:       a=relu(gn(A0)); t=gn(a@lin_w^T); out=relu(t+agts)
// Weights live in LDS as packed bf16 pairs; activations fp32.

#define N_AGT 100000
#define N_CTX 10000
#define NE    1000000
#define D     128

__device__ __forceinline__ float bf_lo(uint32_t u){ return __uint_as_float(u << 16); }
__device__ __forceinline__ float bf_hi(uint32_t u){ return __uint_as_float(u & 0xFFFF0000u); }
__device__ __forceinline__ uint16_t f2bf(float f){
  uint32_t u = __float_as_uint(f);
  u += 0x7FFFu + ((u >> 16) & 1u);   // round-to-nearest-even
  return (uint16_t)(u >> 16);
}
__device__ __forceinline__ float bf2f(uint16_t v){ return __uint_as_float(((uint32_t)v) << 16); }

// Stage a 128x128 f32 matrix W (row-major, row stride rs floats, starting col co)
// into LDS as packed bf16: wp[(p2*128+o)*2 + {0,1}] holds W[o][4*p2 .. 4*p2+3].
__device__ __forceinline__ void stage_w4(uint32_t* wp, const float* __restrict__ W,
                                         int rs, int co, int tid, int nthr){
  for (int idx = tid; idx < 32*128; idx += nthr){
    int p2 = idx & 31, o = idx >> 5;
    const float4 f = *(const float4*)(W + (size_t)o*rs + co + p2*4);
    uint32_t lo = ((uint32_t)f2bf(f.y) << 16) | (uint32_t)f2bf(f.x);
    uint32_t hi = ((uint32_t)f2bf(f.w) << 16) | (uint32_t)f2bf(f.z);
    *(uint2*)&wp[(p2*128 + o)*2] = make_uint2(lo, hi);
  }
}

// dot of x[128] (LDS f32) with packed weight column o: sum_k x[k]*W[o][k]
__device__ __forceinline__ float dot128(const uint32_t* wp, const float* xb, int o){
  float acc = 0.f;
  #pragma unroll 8
  for (int p2 = 0; p2 < 32; p2++){
    const uint2 w = *(const uint2*)&wp[(p2*128 + o)*2];
    const float4 x = *(const float4*)&xb[p2*4];
    acc += x.x*bf_lo(w.x) + x.y*bf_hi(w.x) + x.z*bf_lo(w.y) + x.w*bf_hi(w.y);
  }
  return acc;
}

// 4 edges x 2 outputs register-tiled matmul accumulate: a{0,1}[j] += xb[j] . W[o{0,1}]
__device__ __forceinline__ void mm4x2(const uint32_t* wp, const float (*xb)[128],
                                      int o0, int o1, float a0[4], float a1[4]){
  #pragma unroll 4
  for (int p2 = 0; p2 < 32; p2++){
    const uint2 wA = *(const uint2*)&wp[(p2*128 + o0)*2];
    const uint2 wB = *(const uint2*)&wp[(p2*128 + o1)*2];
    const float wa0 = bf_lo(wA.x), wa1 = bf_hi(wA.x), wa2 = bf_lo(wA.y), wa3 = bf_hi(wA.y);
    const float wb0 = bf_lo(wB.x), wb1 = bf_hi(wB.x), wb2 = bf_lo(wB.y), wb3 = bf_hi(wB.y);
    #pragma unroll
    for (int j = 0; j < 4; j++){
      const float4 x = *(const float4*)&xb[j][p2*4];
      a0[j] += x.x*wa0 + x.y*wa1 + x.z*wa2 + x.w*wa3;
      a1[j] += x.x*wb0 + x.y*wb1 + x.z*wb2 + x.w*wb3;
    }
  }
}

// wave-wide GroupNorm(1 group over 128 ch) + affine (+optional relu); lane owns
// channels o0=lane and o1=lane+64 -> full wave covers the row.
__device__ __forceinline__ void gn2(float& v0, float& v1, float gw0, float gb0,
                                    float gw1, float gb1, bool do_relu){
  float s = v0 + v1, ss = v0*v0 + v1*v1;
  #pragma unroll
  for (int m = 1; m < 64; m <<= 1){ s += __shfl_xor(s, m); ss += __shfl_xor(ss, m); }
  const float mean = s * (1.f/128.f);
  const float var  = ss * (1.f/128.f) - mean*mean;
  const float rs   = rsqrtf(var + 1e-5f);
  v0 = (v0 - mean)*rs*gw0 + gb0;
  v1 = (v1 - mean)*rs*gw1 + gb1;
  if (do_relu){ v0 = fmaxf(v0, 0.f); v1 = fmaxf(v1, 0.f); }
}

// ---------------- k_ctx: CtxP = bf16( ctx @ W1c^T ) ----------------
__global__ __launch_bounds__(128) void k_ctx(const float* __restrict__ ctx,
                                             const float* __restrict__ ctx_w1,
                                             uint16_t* __restrict__ CtxP){
  __shared__ __align__(16) uint32_t wc[32*128*2];
  __shared__ __align__(16) float xbuf[128];
  const int tid = threadIdx.x;
  stage_w4(wc, ctx_w1, 384, 256, tid, 128);
  __syncthreads();
  for (int row = blockIdx.x; row < N_CTX; row += gridDim.x){
    __syncthreads();
    xbuf[tid] = ctx[(size_t)row*D + tid];
    __syncthreads();
    const float acc = dot128(wc, xbuf, tid);
    CtxP[(size_t)row*D + tid] = f2bf(acc);
  }
}

// ---------------- k_agent_pre: QW + A0 ----------------
__global__ __launch_bounds__(256) void k_agent_pre(const float* __restrict__ agts,
    const float* __restrict__ q_w, const float* __restrict__ ctx_w1,
    const float* __restrict__ agt_w, const float* __restrict__ q_gw,
    const float* __restrict__ q_gb, uint16_t* __restrict__ QW,
    float* __restrict__ A0){
  __shared__ __align__(16) uint32_t wq[32*128*2];
  __shared__ __align__(16) uint32_t wa[32*128*2];
  __shared__ __align__(16) uint32_t w1q[32*128*2];
  __shared__ __align__(16) float xbuf[2][128];
  __shared__ __align__(16) float qbuf[2][128];
  __shared__ float scr[8];
  const int tid = threadIdx.x;
  stage_w4(wq,  q_w,    128, 0,   tid, 256);
  stage_w4(wa,  agt_w,  128, 0,   tid, 256);
  stage_w4(w1q, ctx_w1, 384, 128, tid, 256);
  __syncthreads();
  const int half = tid >> 7, o = tid & 127;
  const float qgw = q_gw[o], qgb = q_gb[o];
  const int rowsPerIter = gridDim.x * 2;
  const int nIter = (N_AGT + rowsPerIter - 1) / rowsPerIter;
  for (int it = 0; it < nIter; it++){
    const int row = it*rowsPerIter + blockIdx.x*2 + half;
    const bool ok = row < N_AGT;
    __syncthreads();
    if (ok) xbuf[half][o] = agts[(size_t)row*D + o];
    __syncthreads();
    const float accq = dot128(wq, xbuf[half], o);
    const float acca = dot128(wa, xbuf[half], o);
    if (ok) A0[(size_t)row*D + o] = acca;
    // GN over the 128 threads of this half (2 waves)
    float s = accq, ss = accq*accq;
    #pragma unroll
    for (int m = 1; m < 64; m <<= 1){ s += __shfl_xor(s, m); ss += __shfl_xor(ss, m); }
    const int wvi = tid >> 6;
    __syncthreads();
    if ((tid & 63) == 0){ scr[wvi*2] = s; scr[wvi*2+1] = ss; }
    __syncthreads();
    s  = scr[half*4 + 0] + scr[half*4 + 2];
    ss = scr[half*4 + 1] + scr[half*4 + 3];
    const float mean = s*(1.f/128.f);
    const float var  = ss*(1.f/128.f) - mean*mean;
    const float qv = fmaxf((accq - mean)*rsqrtf(var + 1e-5f)*qgw + qgb, 0.f);
    __syncthreads();
    qbuf[half][o] = qv;
    __syncthreads();
    const float acc2 = dot128(w1q, qbuf[half], o);
    if (ok) QW[(size_t)row*D + o] = f2bf(acc2);
  }
}

// ---------------- k_edge: fused per-edge pipeline ----------------
__global__ __launch_bounds__(512) void k_edge(const float* __restrict__ agt_ctrs,
    const float* __restrict__ ctx_ctrs, const int* __restrict__ hi,
    const int* __restrict__ wi, const float* __restrict__ dist_w1,
    const float* __restrict__ dist_b1, const float* __restrict__ dist_w2,
    const float* __restrict__ ctx_w1, const float* __restrict__ ctx_w2,
    const float* __restrict__ dist_gw, const float* __restrict__ dist_gb,
    const float* __restrict__ ctx_gw, const float* __restrict__ ctx_gb,
    const uint16_t* __restrict__ QW, const uint16_t* __restrict__ CtxP,
    float* __restrict__ A0){
  __shared__ __align__(16) uint32_t wp_d2 [32*128*2];
  __shared__ __align__(16) uint32_t wp_w1d[32*128*2];
  __shared__ __align__(16) uint32_t wp_c2 [32*128*2];
  __shared__ __align__(16) float xbuf[8][4][128];
  const int tid = threadIdx.x;
  stage_w4(wp_d2,  dist_w2, 128, 0, tid, 512);
  stage_w4(wp_w1d, ctx_w1,  384, 0, tid, 512);
  stage_w4(wp_c2,  ctx_w2,  128, 0, tid, 512);
  __syncthreads();
  const int wv = tid >> 6, lane = tid & 63;
  const int o0 = lane, o1 = lane + 64;
  const float2 w1a = *(const float2*)&dist_w1[o0*2];
  const float2 w1b = *(const float2*)&dist_w1[o1*2];
  const float b1a = dist_b1[o0], b1b = dist_b1[o1];
  const float dgwa = dist_gw[o0], dgba = dist_gb[o0];
  const float dgwb = dist_gw[o1], dgbb = dist_gb[o1];
  const float cgwa = ctx_gw[o0],  cgba = ctx_gb[o0];
  const float cgwb = ctx_gw[o1],  cgbb = ctx_gb[o1];
  float (*xb)[128] = xbuf[wv];
  const int gwav = blockIdx.x * 8 + wv;
  for (int c = gwav; c < NE/4; c += 256*8){
    const int e0 = c * 4;
    int h[4], w[4];
    float a0[4], a1[4];
    #pragma unroll
    for (int j = 0; j < 4; j++){
      h[j] = hi[e0 + j]; w[j] = wi[e0 + j];
      const float2 ac = *(const float2*)&agt_ctrs[(size_t)h[j]*2];
      const float2 cc = *(const float2*)&ctx_ctrs[(size_t)w[j]*2];
      const float dx = ac.x - cc.x, dy = ac.y - cc.y;
      xb[j][o0] = fmaxf(fmaf(dx, w1a.x, fmaf(dy, w1a.y, b1a)), 0.f);
      xb[j][o1] = fmaxf(fmaf(dx, w1b.x, fmaf(dy, w1b.y, b1b)), 0.f);
    }
    asm volatile("s_waitcnt lgkmcnt(0)" ::: "memory");
    #pragma unroll
    for (int j = 0; j < 4; j++){ a0[j] = 0.f; a1[j] = 0.f; }
    mm4x2(wp_d2, (const float(*)[128])xb, o0, o1, a0, a1);           // z = d1 @ W2^T
    #pragma unroll
    for (int j = 0; j < 4; j++) gn2(a0[j], a1[j], dgwa, dgba, dgwb, dgbb, true);
    #pragma unroll
    for (int j = 0; j < 4; j++){ xb[j][o0] = a0[j]; xb[j][o1] = a1[j]; }
    asm volatile("s_waitcnt lgkmcnt(0)" ::: "memory");
    #pragma unroll
    for (int j = 0; j < 4; j++){                                      // s init = QW[hi] + CtxP[wi]
      a0[j] = bf2f(QW[(size_t)h[j]*D + o0]) + bf2f(CtxP[(size_t)w[j]*D + o0]);
      a1[j] = bf2f(QW[(size_t)h[j]*D + o1]) + bf2f(CtxP[(size_t)w[j]*D + o1]);
    }
    mm4x2(wp_w1d, (const float(*)[128])xb, o0, o1, a0, a1);          // s += d @ W1d^T
    #pragma unroll
    for (int j = 0; j < 4; j++) gn2(a0[j], a1[j], cgwa, cgba, cgwb, cgbb, true);
    #pragma unroll
    for (int j = 0; j < 4; j++){ xb[j][o0] = a0[j]; xb[j][o1] = a1[j]; }
    asm volatile("s_waitcnt lgkmcnt(0)" ::: "memory");
    #pragma unroll
    for (int j = 0; j < 4; j++){ a0[j] = 0.f; a1[j] = 0.f; }
    mm4x2(wp_c2, (const float(*)[128])xb, o0, o1, a0, a1);           // c = c1 @ Wc2^T
    #pragma unroll
    for (int j = 0; j < 4; j++){
      atomicAdd(&A0[(size_t)h[j]*D + o0], a0[j]);
      atomicAdd(&A0[(size_t)h[j]*D + o1], a1[j]);
    }
  }
}

// ---------------- k_post: finalize per agent row (in-place on d_out) ----------------
__device__ __forceinline__ void red128(float& s, float& ss, float* scr, int tid){
  #pragma unroll
  for (int m = 1; m < 64; m <<= 1){ s += __shfl_xor(s, m); ss += __shfl_xor(ss, m); }
  __syncthreads();
  if ((tid & 63) == 0){ scr[(tid>>6)*2] = s; scr[(tid>>6)*2+1] = ss; }
  __syncthreads();
  s = scr[0] + scr[2]; ss = scr[1] + scr[3];
}

__global__ __launch_bounds__(128) void k_post(float* __restrict__ A0,
    const float* __restrict__ agts, const float* __restrict__ lin_w,
    const float* __restrict__ norm_gw, const float* __restrict__ norm_gb,
    const float* __restrict__ lin_gw, const float* __restrict__ lin_gb){
  __shared__ __align__(16) uint32_t wl[32*128*2];
  __shared__ __align__(16) float abuf[128];
  __shared__ float scr[4];
  const int tid = threadIdx.x;
  stage_w4(wl, lin_w, 128, 0, tid, 128);
  __syncthreads();
  const float ngw = norm_gw[tid], ngb = norm_gb[tid];
  const float lgw = lin_gw[tid],  lgb = lin_gb[tid];
  for (int row = blockIdx.x; row < N_AGT; row += gridDim.x){
    float a = A0[(size_t)row*D + tid];
    float s = a, ss = a*a;
    red128(s, ss, scr, tid);
    float mean = s*(1.f/128.f), var = ss*(1.f/128.f) - mean*mean;
    a = fmaxf((a - mean)*rsqrtf(var + 1e-5f)*ngw + ngb, 0.f);
    __syncthreads();
    abuf[tid] = a;
    __syncthreads();
    float t = dot128(wl, abuf, tid);
    s = t; ss = t*t;
    red128(s, ss, scr, tid);
    mean = s*(1.f/128.f); var = ss*(1.f/128.f) - mean*mean;
    t = (t - mean)*rsqrtf(var + 1e-5f)*lgw + lgb;
    A0[(size_t)row*D + tid] = fmaxf(t + agts[(size_t)row*D + tid], 0.f);
  }
}

extern "C" void kernel_launch(void* const* d_in, const int* in_sizes, int n_in,
                              void* d_out, int out_size, void* d_ws, size_t ws_size,
                              hipStream_t stream){
  const float* agts     = (const float*)d_in[0];
  const float* ctx      = (const float*)d_in[1];
  const float* agt_ctrs = (const float*)d_in[2];
  const float* ctx_ctrs = (const float*)d_in[3];
  const int*   hi       = (const int*)d_in[4];
  const int*   wi       = (const int*)d_in[5];
  const float* dist_w1  = (const float*)d_in[6];
  const float* dist_b1  = (const float*)d_in[7];
  const float* dist_w2  = (const float*)d_in[8];
  const float* dist_gw  = (const float*)d_in[9];
  const float* dist_gb  = (const float*)d_in[10];
  const float* q_w      = (const float*)d_in[11];
  const float* q_gw     = (const float*)d_in[12];
  const float* q_gb     = (const float*)d_in[13];
  const float* ctx_w1   = (const float*)d_in[14];
  const float* ctx_gw   = (const float*)d_in[15];
  const float* ctx_gb   = (const float*)d_in[16];
  const float* ctx_w2   = (const float*)d_in[17];
  const float* agt_w    = (const float*)d_in[18];
  const float* norm_gw  = (const float*)d_in[19];
  const float* norm_gb  = (const float*)d_in[20];
  const float* lin_w    = (const float*)d_in[21];
  const float* lin_gw   = (const float*)d_in[22];
  const float* lin_gb   = (const float*)d_in[23];

  uint16_t* QW   = (uint16_t*)d_ws;                 // 100000*128 bf16 = 25.6 MB
  uint16_t* CtxP = QW + (size_t)N_AGT * D;          // +2.56 MB
  float*    A0   = (float*)d_out;                   // accumulator lives in d_out

  k_ctx<<<1024, 128, 0, stream>>>(ctx, ctx_w1, CtxP);
  k_agent_pre<<<256, 256, 0, stream>>>(agts, q_w, ctx_w1, agt_w, q_gw, q_gb, QW, A0);
  k_edge<<<256, 512, 0, stream>>>(agt_ctrs, ctx_ctrs, hi, wi, dist_w1, dist_b1,
                                  dist_w2, ctx_w1, ctx_w2, dist_gw, dist_gb,
                                  ctx_gw, ctx_gb, QW, CtxP, A0);
  k_post<<<2048, 128, 0, stream>>>(A0, agts, lin_w, norm_gw, norm_gb, lin_gw, lin_gb);
}

// Round 2
// 1640.925 us; speedup vs baseline: 2.4303x; 2.4303x over previous
//
#include <hip/hip_runtime.h>
#include <stdint.h>

// GreatNet: agent/context edge MLP.
//   k_ctx:        CtxP[j]  = ctx[j] @ W1c^T                       (bf16, ws)
//   k_agent_pre:  QW[i]    = relu(gn(agts[i]@q_w^T)) @ W1q^T      (bf16, ws)
//                 A0[i]    = agts[i] @ agt_w^T                    (f32, d_out)
//   k_edge_mfma:  per edge: d1=relu(d0@w1^T+b1); d=relu(gn(d1@W2^T));
//                 s = d@W1d^T + QW[hi] + CtxP[wi]; c1=relu(gn(s));
//                 c = c1@Wc2^T;  atomicAdd(A0[hi], c)   [MFMA bf16]
//   k_post:       a=relu(gn(A0)); t=gn(a@lin_w^T); out=relu(t+agts)

#define N_AGT 100000
#define N_CTX 10000
#define NE    1000000
#define D     128

typedef __attribute__((ext_vector_type(8))) __bf16 bf16x8;
typedef __attribute__((ext_vector_type(4))) float f32x4;
typedef __attribute__((ext_vector_type(4))) unsigned int uint32x4;
typedef __attribute__((ext_vector_type(8))) unsigned short ushort8;

__device__ __forceinline__ float bf_lo(uint32_t u){ return __uint_as_float(u << 16); }
__device__ __forceinline__ float bf_hi(uint32_t u){ return __uint_as_float(u & 0xFFFF0000u); }
__device__ __forceinline__ uint16_t f2bf(float f){
  uint32_t u = __float_as_uint(f);
  u += 0x7FFFu + ((u >> 16) & 1u);   // round-to-nearest-even
  return (uint16_t)(u >> 16);
}
__device__ __forceinline__ float bf2f(uint16_t v){ return __uint_as_float(((uint32_t)v) << 16); }

__device__ __forceinline__ f32x4 mfma16(bf16x8 a, bf16x8 b, f32x4 c){
  return __builtin_amdgcn_mfma_f32_16x16x32_bf16(a, b, c, 0, 0, 0);
}

// ======================= MFMA edge kernel =======================
// LDS layout (dynamic, 123648 B):
//   [0)      wd2  32768  bf16 128x128 swizzled  (dist_w2, B-frag source)
//   [32768)  w1d  32768  (ctx_w1 cols 0:128)
//   [65536)  wc2  32768  (ctx_w2)
//   [98304)  xb   2 x 48x256B activation tiles (one per group), swizzled
//   [122880) hb   2 x 96 ints (h[48], w[48] per group)
// Swizzle: phys = row*256 + (byteInRow ^ ((row&7)<<4)).  All b128 frag reads
// (stride-256B rows, the 16-way-conflict pattern) become ~2-way = free.

__device__ __forceinline__ void stage_wsz(char* dst, const float* __restrict__ W,
                                          int rs, int co, int tid){
  for (int idx = tid; idx < 128*16; idx += 512){
    const int row = idx >> 4, ch = idx & 15;
    const float4 f0 = *(const float4*)(W + (size_t)row*rs + co + ch*8);
    const float4 f1 = *(const float4*)(W + (size_t)row*rs + co + ch*8 + 4);
    ushort8 u;
    u[0]=f2bf(f0.x); u[1]=f2bf(f0.y); u[2]=f2bf(f0.z); u[3]=f2bf(f0.w);
    u[4]=f2bf(f1.x); u[5]=f2bf(f1.y); u[6]=f2bf(f1.z); u[7]=f2bf(f1.w);
    *(uint32x4*)(dst + row*256 + ((ch*16) ^ ((row&7)<<4))) = __builtin_bit_cast(uint32x4, u);
  }
}

__device__ __forceinline__ bf16x8 ldfrag(const char* base, int row, int cb){
  return __builtin_bit_cast(bf16x8,
      *(const uint32x4*)(base + row*256 + (cb ^ ((row&7)<<4))));
}

// one matmul stage: acc[mt][ntl] += xb[48x128] @ wm^T (wave's 32-col slice)
__device__ __forceinline__ void mm_stage(const char* xb, const char* wm, int wv,
                                         int llo, int lhi, f32x4 acc[3][2]){
  #pragma unroll
  for (int kt = 0; kt < 4; kt++){
    const int cb = kt*64 + lhi*16;
    const bf16x8 b0 = ldfrag(wm, wv*32 + llo,      cb);
    const bf16x8 b1 = ldfrag(wm, wv*32 + 16 + llo, cb);
    #pragma unroll
    for (int mt = 0; mt < 3; mt++){
      const bf16x8 a = ldfrag(xb, mt*16 + llo, cb);
      acc[mt][0] = mfma16(a, b0, acc[mt][0]);
      acc[mt][1] = mfma16(a, b1, acc[mt][1]);
    }
  }
}

// row-pass GroupNorm over the 48x128 tile (each wave owns 12 rows; 16 lanes
// per row, 8 cols per lane). In-place on bf16 tile.
__device__ __forceinline__ void gn_rowpass(char* xb, const int rr[3], int llo,
                                           const float gw[8], const float gb[8]){
  #pragma unroll
  for (int i = 0; i < 3; i++){
    const int row = rr[i];
    char* p = xb + row*256 + ((llo*16) ^ ((row&7)<<4));
    ushort8 u = __builtin_bit_cast(ushort8, *(const uint32x4*)p);
    float f[8]; float s = 0.f, ss = 0.f;
    #pragma unroll
    for (int j = 0; j < 8; j++){ f[j] = bf2f(u[j]); s += f[j]; ss += f[j]*f[j]; }
    #pragma unroll
    for (int m = 1; m < 16; m <<= 1){ s += __shfl_xor(s, m); ss += __shfl_xor(ss, m); }
    const float mean = s*(1.f/128.f);
    const float var  = ss*(1.f/128.f) - mean*mean;
    const float rstd = rsqrtf(var + 1e-5f);
    #pragma unroll
    for (int j = 0; j < 8; j++){
      const float g = fmaxf((f[j]-mean)*rstd*gw[j] + gb[j], 0.f);
      u[j] = f2bf(g);
    }
    *(uint32x4*)p = __builtin_bit_cast(uint32x4, u);
  }
}

#define NITER ((NE + 95) / 96)

__global__ __launch_bounds__(512, 2) void k_edge_mfma(
    const float* __restrict__ agt_ctrs, const float* __restrict__ ctx_ctrs,
    const int* __restrict__ hi, const int* __restrict__ wi,
    const float* __restrict__ dist_w1, const float* __restrict__ dist_b1,
    const float* __restrict__ dist_gw, const float* __restrict__ dist_gb,
    const float* __restrict__ ctx_gw, const float* __restrict__ ctx_gb,
    const float* __restrict__ dist_w2, const float* __restrict__ ctx_w1,
    const float* __restrict__ ctx_w2,
    const uint16_t* __restrict__ QW, const uint16_t* __restrict__ CtxP,
    float* __restrict__ A0){
  extern __shared__ __align__(16) char smem[];
  const int tid  = threadIdx.x;
  const int wave = tid >> 6, lane = tid & 63;
  const int grp  = wave >> 2, wv = wave & 3;
  const int lhi  = lane >> 4, llo = lane & 15;

  stage_wsz(smem,         dist_w2, 128, 0, tid);
  stage_wsz(smem + 32768, ctx_w1,  384, 0, tid);
  stage_wsz(smem + 65536, ctx_w2,  128, 0, tid);

  char* xb = smem + 98304 + grp*12288;
  int*  hb = (int*)(smem + 122880) + grp*96;

  // per-lane params: this lane's 8 cols in row-pass / d1 roles are c0..c0+7
  const int c0 = llo*8;
  float w1x[8], w1y[8], b1v[8], dgw[8], dgb[8], cgw[8], cgb[8];
  #pragma unroll
  for (int j = 0; j < 8; j++){
    w1x[j] = dist_w1[(c0+j)*2 + 0];
    w1y[j] = dist_w1[(c0+j)*2 + 1];
    b1v[j] = dist_b1[c0+j];
    dgw[j] = dist_gw[c0+j]; dgb[j] = dist_gb[c0+j];
    cgw[j] = ctx_gw[c0+j];  cgb[j] = ctx_gb[c0+j];
  }
  __syncthreads();   // weights staged

  for (int it = blockIdx.x; it < NITER; it += gridDim.x){
    const long ebase = (long)it*96 + grp*48;
    // ---- 1. indices ----
    if (wv == 0 && lane < 48){
      const long e = ebase + lane;
      int h = 0, w = 0;
      if (e < NE){ h = hi[e]; w = wi[e]; }
      hb[lane] = h; hb[48 + lane] = w;
    }
    __syncthreads();
    // ---- 2. issue gathers + build d1 ----
    int rr[3], rh[3], rw[3];
    ushort8 qg[3], cg[3];
    float2 acs[3], ccs[3];
    #pragma unroll
    for (int i = 0; i < 3; i++){
      rr[i] = wv*12 + i*4 + lhi;
      rh[i] = hb[rr[i]]; rw[i] = hb[48 + rr[i]];
      qg[i]  = *(const ushort8*)&QW  [(size_t)rh[i]*D + c0];
      cg[i]  = *(const ushort8*)&CtxP[(size_t)rw[i]*D + c0];
      acs[i] = *(const float2*)&agt_ctrs[(size_t)rh[i]*2];
      ccs[i] = *(const float2*)&ctx_ctrs[(size_t)rw[i]*2];
    }
    #pragma unroll
    for (int i = 0; i < 3; i++){
      const float dx = acs[i].x - ccs[i].x, dy = acs[i].y - ccs[i].y;
      ushort8 u;
      #pragma unroll
      for (int j = 0; j < 8; j++)
        u[j] = f2bf(fmaxf(fmaf(dx, w1x[j], fmaf(dy, w1y[j], b1v[j])), 0.f));
      *(uint32x4*)(xb + rr[i]*256 + ((llo*16) ^ ((rr[i]&7)<<4))) =
          __builtin_bit_cast(uint32x4, u);
    }
    __syncthreads();            // xb = d1
    // ---- 3. MFMA1: z = d1 @ W2^T ----
    f32x4 acc1[3][2];
    #pragma unroll
    for (int mt = 0; mt < 3; mt++){ acc1[mt][0] = (f32x4)0.f; acc1[mt][1] = (f32x4)0.f; }
    mm_stage(xb, smem, wv, llo, lhi, acc1);
    __syncthreads();            // xb (d1) consumed
    // ---- 4. stage qc = QW[h]+CtxP[w] into xb ----
    #pragma unroll
    for (int i = 0; i < 3; i++){
      ushort8 u;
      #pragma unroll
      for (int j = 0; j < 8; j++) u[j] = f2bf(bf2f(qg[i][j]) + bf2f(cg[i][j]));
      *(uint32x4*)(xb + rr[i]*256 + ((llo*16) ^ ((rr[i]&7)<<4))) =
          __builtin_bit_cast(uint32x4, u);
    }
    __syncthreads();            // xb = qc
    // ---- 5. acc2 init from qc (C-frag ownership) ----
    f32x4 acc2[3][2];
    #pragma unroll
    for (int mt = 0; mt < 3; mt++)
      #pragma unroll
      for (int ntl = 0; ntl < 2; ntl++)
        #pragma unroll
        for (int r = 0; r < 4; r++){
          const int m = mt*16 + lhi*4 + r;
          const int n = wv*32 + ntl*16 + llo;
          acc2[mt][ntl][r] = bf2f(*(const uint16_t*)(xb + m*256 + ((n*2) ^ ((m&7)<<4))));
        }
    __syncthreads();            // qc consumed
    // ---- 6. GN1: scatter raw z, row-pass normalize -> xb = d ----
    #pragma unroll
    for (int mt = 0; mt < 3; mt++)
      #pragma unroll
      for (int ntl = 0; ntl < 2; ntl++)
        #pragma unroll
        for (int r = 0; r < 4; r++){
          const int m = mt*16 + lhi*4 + r;
          const int n = wv*32 + ntl*16 + llo;
          *(uint16_t*)(xb + m*256 + ((n*2) ^ ((m&7)<<4))) = f2bf(acc1[mt][ntl][r]);
        }
    __syncthreads();
    gn_rowpass(xb, rr, llo, dgw, dgb);
    __syncthreads();            // xb = d
    // ---- 7. MFMA2: s = qc + d @ W1d^T ----
    mm_stage(xb, smem + 32768, wv, llo, lhi, acc2);
    __syncthreads();            // xb (d) consumed
    // ---- 8. GN2 -> xb = c1 ----
    #pragma unroll
    for (int mt = 0; mt < 3; mt++)
      #pragma unroll
      for (int ntl = 0; ntl < 2; ntl++)
        #pragma unroll
        for (int r = 0; r < 4; r++){
          const int m = mt*16 + lhi*4 + r;
          const int n = wv*32 + ntl*16 + llo;
          *(uint16_t*)(xb + m*256 + ((n*2) ^ ((m&7)<<4))) = f2bf(acc2[mt][ntl][r]);
        }
    __syncthreads();
    gn_rowpass(xb, rr, llo, cgw, cgb);
    __syncthreads();            // xb = c1
    // ---- 9. MFMA3 + scatter-add ----
    f32x4 acc3[3][2];
    #pragma unroll
    for (int mt = 0; mt < 3; mt++){ acc3[mt][0] = (f32x4)0.f; acc3[mt][1] = (f32x4)0.f; }
    mm_stage(xb, smem + 65536, wv, llo, lhi, acc3);
    #pragma unroll
    for (int mt = 0; mt < 3; mt++)
      #pragma unroll
      for (int ntl = 0; ntl < 2; ntl++)
        #pragma unroll
        for (int r = 0; r < 4; r++){
          const int m = mt*16 + lhi*4 + r;
          if (ebase + m < NE){
            const int n = wv*32 + ntl*16 + llo;
            atomicAdd(&A0[(size_t)hb[m]*D + n], acc3[mt][ntl][r]);
          }
        }
    __syncthreads();            // xb/hb reusable next iter
  }
}

// ======================= legacy VALU kernels (unchanged) =======================

__device__ __forceinline__ void stage_w4(uint32_t* wp, const float* __restrict__ W,
                                         int rs, int co, int tid, int nthr){
  for (int idx = tid; idx < 32*128; idx += nthr){
    int p2 = idx & 31, o = idx >> 5;
    const float4 f = *(const float4*)(W + (size_t)o*rs + co + p2*4);
    uint32_t lo = ((uint32_t)f2bf(f.y) << 16) | (uint32_t)f2bf(f.x);
    uint32_t hi = ((uint32_t)f2bf(f.w) << 16) | (uint32_t)f2bf(f.z);
    *(uint2*)&wp[(p2*128 + o)*2] = make_uint2(lo, hi);
  }
}

__device__ __forceinline__ float dot128(const uint32_t* wp, const float* xb, int o){
  float acc = 0.f;
  #pragma unroll 8
  for (int p2 = 0; p2 < 32; p2++){
    const uint2 w = *(const uint2*)&wp[(p2*128 + o)*2];
    const float4 x = *(const float4*)&xb[p2*4];
    acc += x.x*bf_lo(w.x) + x.y*bf_hi(w.x) + x.z*bf_lo(w.y) + x.w*bf_hi(w.y);
  }
  return acc;
}

__global__ __launch_bounds__(128) void k_ctx(const float* __restrict__ ctx,
                                             const float* __restrict__ ctx_w1,
                                             uint16_t* __restrict__ CtxP){
  __shared__ __align__(16) uint32_t wc[32*128*2];
  __shared__ __align__(16) float xbuf[128];
  const int tid = threadIdx.x;
  stage_w4(wc, ctx_w1, 384, 256, tid, 128);
  __syncthreads();
  for (int row = blockIdx.x; row < N_CTX; row += gridDim.x){
    __syncthreads();
    xbuf[tid] = ctx[(size_t)row*D + tid];
    __syncthreads();
    const float acc = dot128(wc, xbuf, tid);
    CtxP[(size_t)row*D + tid] = f2bf(acc);
  }
}

__global__ __launch_bounds__(256) void k_agent_pre(const float* __restrict__ agts,
    const float* __restrict__ q_w, const float* __restrict__ ctx_w1,
    const float* __restrict__ agt_w, const float* __restrict__ q_gw,
    const float* __restrict__ q_gb, uint16_t* __restrict__ QW,
    float* __restrict__ A0){
  __shared__ __align__(16) uint32_t wq[32*128*2];
  __shared__ __align__(16) uint32_t wa[32*128*2];
  __shared__ __align__(16) uint32_t w1q[32*128*2];
  __shared__ __align__(16) float xbuf[2][128];
  __shared__ __align__(16) float qbuf[2][128];
  __shared__ float scr[8];
  const int tid = threadIdx.x;
  stage_w4(wq,  q_w,    128, 0,   tid, 256);
  stage_w4(wa,  agt_w,  128, 0,   tid, 256);
  stage_w4(w1q, ctx_w1, 384, 128, tid, 256);
  __syncthreads();
  const int half = tid >> 7, o = tid & 127;
  const float qgw = q_gw[o], qgb = q_gb[o];
  const int rowsPerIter = gridDim.x * 2;
  const int nIter = (N_AGT + rowsPerIter - 1) / rowsPerIter;
  for (int it = 0; it < nIter; it++){
    const int row = it*rowsPerIter + blockIdx.x*2 + half;
    const bool ok = row < N_AGT;
    __syncthreads();
    if (ok) xbuf[half][o] = agts[(size_t)row*D + o];
    __syncthreads();
    const float accq = dot128(wq, xbuf[half], o);
    const float acca = dot128(wa, xbuf[half], o);
    if (ok) A0[(size_t)row*D + o] = acca;
    float s = accq, ss = accq*accq;
    #pragma unroll
    for (int m = 1; m < 64; m <<= 1){ s += __shfl_xor(s, m); ss += __shfl_xor(ss, m); }
    const int wvi = tid >> 6;
    __syncthreads();
    if ((tid & 63) == 0){ scr[wvi*2] = s; scr[wvi*2+1] = ss; }
    __syncthreads();
    s  = scr[half*4 + 0] + scr[half*4 + 2];
    ss = scr[half*4 + 1] + scr[half*4 + 3];
    const float mean = s*(1.f/128.f);
    const float var  = ss*(1.f/128.f) - mean*mean;
    const float qv = fmaxf((accq - mean)*rsqrtf(var + 1e-5f)*qgw + qgb, 0.f);
    __syncthreads();
    qbuf[half][o] = qv;
    __syncthreads();
    const float acc2 = dot128(w1q, qbuf[half], o);
    if (ok) QW[(size_t)row*D + o] = f2bf(acc2);
  }
}

__device__ __forceinline__ void red128(float& s, float& ss, float* scr, int tid){
  #pragma unroll
  for (int m = 1; m < 64; m <<= 1){ s += __shfl_xor(s, m); ss += __shfl_xor(ss, m); }
  __syncthreads();
  if ((tid & 63) == 0){ scr[(tid>>6)*2] = s; scr[(tid>>6)*2+1] = ss; }
  __syncthreads();
  s = scr[0] + scr[2]; ss = scr[1] + scr[3];
}

__global__ __launch_bounds__(128) void k_post(float* __restrict__ A0,
    const float* __restrict__ agts, const float* __restrict__ lin_w,
    const float* __restrict__ norm_gw, const float* __restrict__ norm_gb,
    const float* __restrict__ lin_gw, const float* __restrict__ lin_gb){
  __shared__ __align__(16) uint32_t wl[32*128*2];
  __shared__ __align__(16) float abuf[128];
  __shared__ float scr[4];
  const int tid = threadIdx.x;
  stage_w4(wl, lin_w, 128, 0, tid, 128);
  __syncthreads();
  const float ngw = norm_gw[tid], ngb = norm_gb[tid];
  const float lgw = lin_gw[tid],  lgb = lin_gb[tid];
  for (int row = blockIdx.x; row < N_AGT; row += gridDim.x){
    float a = A0[(size_t)row*D + tid];
    float s = a, ss = a*a;
    red128(s, ss, scr, tid);
    float mean = s*(1.f/128.f), var = ss*(1.f/128.f) - mean*mean;
    a = fmaxf((a - mean)*rsqrtf(var + 1e-5f)*ngw + ngb, 0.f);
    __syncthreads();
    abuf[tid] = a;
    __syncthreads();
    float t = dot128(wl, abuf, tid);
    s = t; ss = t*t;
    red128(s, ss, scr, tid);
    mean = s*(1.f/128.f); var = ss*(1.f/128.f) - mean*mean;
    t = (t - mean)*rsqrtf(var + 1e-5f)*lgw + lgb;
    A0[(size_t)row*D + tid] = fmaxf(t + agts[(size_t)row*D + tid], 0.f);
  }
}

extern "C" void kernel_launch(void* const* d_in, const int* in_sizes, int n_in,
                              void* d_out, int out_size, void* d_ws, size_t ws_size,
                              hipStream_t stream){
  const float* agts     = (const float*)d_in[0];
  const float* ctx      = (const float*)d_in[1];
  const float* agt_ctrs = (const float*)d_in[2];
  const float* ctx_ctrs = (const float*)d_in[3];
  const int*   hi       = (const int*)d_in[4];
  const int*   wi       = (const int*)d_in[5];
  const float* dist_w1  = (const float*)d_in[6];
  const float* dist_b1  = (const float*)d_in[7];
  const float* dist_w2  = (const float*)d_in[8];
  const float* dist_gw  = (const float*)d_in[9];
  const float* dist_gb  = (const float*)d_in[10];
  const float* q_w      = (const float*)d_in[11];
  const float* q_gw     = (const float*)d_in[12];
  const float* q_gb     = (const float*)d_in[13];
  const float* ctx_w1   = (const float*)d_in[14];
  const float* ctx_gw   = (const float*)d_in[15];
  const float* ctx_gb   = (const float*)d_in[16];
  const float* ctx_w2   = (const float*)d_in[17];
  const float* agt_w    = (const float*)d_in[18];
  const float* norm_gw  = (const float*)d_in[19];
  const float* norm_gb  = (const float*)d_in[20];
  const float* lin_w    = (const float*)d_in[21];
  const float* lin_gw   = (const float*)d_in[22];
  const float* lin_gb   = (const float*)d_in[23];

  uint16_t* QW   = (uint16_t*)d_ws;                 // 100000*128 bf16 = 25.6 MB
  uint16_t* CtxP = QW + (size_t)N_AGT * D;          // +2.56 MB
  float*    A0   = (float*)d_out;                   // accumulator lives in d_out

  const int EDGE_LDS = 123648;
  hipFuncSetAttribute((const void*)k_edge_mfma,
                      hipFuncAttributeMaxDynamicSharedMemorySize, EDGE_LDS);

  k_ctx<<<1024, 128, 0, stream>>>(ctx, ctx_w1, CtxP);
  k_agent_pre<<<256, 256, 0, stream>>>(agts, q_w, ctx_w1, agt_w, q_gw, q_gb, QW, A0);
  k_edge_mfma<<<256, 512, EDGE_LDS, stream>>>(agt_ctrs, ctx_ctrs, hi, wi,
      dist_w1, dist_b1, dist_gw, dist_gb, ctx_gw, ctx_gb,
      dist_w2, ctx_w1, ctx_w2, QW, CtxP, A0);
  k_post<<<2048, 128, 0, stream>>>(A0, agts, lin_w, norm_gw, norm_gb, lin_gw, lin_gb);
}

// Round 3
// 696.566 us; speedup vs baseline: 5.7251x; 2.3557x over previous
//
#include <hip/hip_runtime.h>
#include <stdint.h>

// GreatNet: agent/context edge MLP.
//   k_ctx:          CtxP[j]  = ctx[j] @ W1c^T                       (bf16, ws)
//   k_agent_pre_mfma: QW[i]  = relu(gn(agts[i]@q_w^T)) @ W1q^T      (bf16, ws)
//                   A0[i]    = agts[i] @ agt_w^T                    (f32, d_out)
//   k_edge_mfma:    per edge: d1=relu(d0@w1^T+b1); d=relu(gn(d1@W2^T));
//                   s = d@W1d^T + QW[hi] + CtxP[wi]; c1=relu(gn(s));
//                   c = c1@Wc2^T;  atomicAdd(A0[hi], c)   [MFMA bf16]
//   k_post_mfma:    a=relu(gn(A0)); t=gn(a@lin_w^T); out=relu(t+agts)

#define N_AGT 100000
#define N_CTX 10000
#define NE    1000000
#define D     128

typedef __attribute__((ext_vector_type(8))) __bf16 bf16x8;
typedef __attribute__((ext_vector_type(4))) float f32x4;
typedef __attribute__((ext_vector_type(4))) unsigned int uint32x4;
typedef __attribute__((ext_vector_type(8))) unsigned short ushort8;

__device__ __forceinline__ float bf_lo(uint32_t u){ return __uint_as_float(u << 16); }
__device__ __forceinline__ float bf_hi(uint32_t u){ return __uint_as_float(u & 0xFFFF0000u); }
__device__ __forceinline__ uint16_t f2bf(float f){
  uint32_t u = __float_as_uint(f);
  u += 0x7FFFu + ((u >> 16) & 1u);   // round-to-nearest-even
  return (uint16_t)(u >> 16);
}
__device__ __forceinline__ float bf2f(uint16_t v){ return __uint_as_float(((uint32_t)v) << 16); }

__device__ __forceinline__ f32x4 mfma16(bf16x8 a, bf16x8 b, f32x4 c){
  return __builtin_amdgcn_mfma_f32_16x16x32_bf16(a, b, c, 0, 0, 0);
}

// ---- shared MFMA tile machinery (swizzle: phys = row*256 + (byte ^ ((row&7)<<4))) ----

__device__ __forceinline__ void stage_wsz(char* dst, const float* __restrict__ W,
                                          int rs, int co, int tid){
  for (int idx = tid; idx < 128*16; idx += 512){
    const int row = idx >> 4, ch = idx & 15;
    const float4 f0 = *(const float4*)(W + (size_t)row*rs + co + ch*8);
    const float4 f1 = *(const float4*)(W + (size_t)row*rs + co + ch*8 + 4);
    ushort8 u;
    u[0]=f2bf(f0.x); u[1]=f2bf(f0.y); u[2]=f2bf(f0.z); u[3]=f2bf(f0.w);
    u[4]=f2bf(f1.x); u[5]=f2bf(f1.y); u[6]=f2bf(f1.z); u[7]=f2bf(f1.w);
    *(uint32x4*)(dst + row*256 + ((ch*16) ^ ((row&7)<<4))) = __builtin_bit_cast(uint32x4, u);
  }
}

__device__ __forceinline__ bf16x8 ldfrag(const char* base, int row, int cb){
  return __builtin_bit_cast(bf16x8,
      *(const uint32x4*)(base + row*256 + (cb ^ ((row&7)<<4))));
}

__device__ __forceinline__ void mm_stage(const char* xb, const char* wm, int wv,
                                         int llo, int lhi, f32x4 acc[3][2]){
  #pragma unroll
  for (int kt = 0; kt < 4; kt++){
    const int cb = kt*64 + lhi*16;
    const bf16x8 b0 = ldfrag(wm, wv*32 + llo,      cb);
    const bf16x8 b1 = ldfrag(wm, wv*32 + 16 + llo, cb);
    #pragma unroll
    for (int mt = 0; mt < 3; mt++){
      const bf16x8 a = ldfrag(xb, mt*16 + llo, cb);
      acc[mt][0] = mfma16(a, b0, acc[mt][0]);
      acc[mt][1] = mfma16(a, b1, acc[mt][1]);
    }
  }
}

// scatter a 48x128 acc (3x2 frags) into the swizzled bf16 tile
__device__ __forceinline__ void scat_acc(char* xb, const f32x4 acc[3][2],
                                         int wv, int llo, int lhi){
  #pragma unroll
  for (int mt = 0; mt < 3; mt++)
    #pragma unroll
    for (int ntl = 0; ntl < 2; ntl++)
      #pragma unroll
      for (int r = 0; r < 4; r++){
        const int m = mt*16 + lhi*4 + r;
        const int n = wv*32 + ntl*16 + llo;
        *(uint16_t*)(xb + m*256 + ((n*2) ^ ((m&7)<<4))) = f2bf(acc[mt][ntl][r]);
      }
}

// row-pass GroupNorm over 48x128 tile (wave owns 12 rows; 16 lanes/row, 8 cols/lane)
__device__ __forceinline__ void gn_rowpass(char* xb, const int rr[3], int llo,
                                           const float gw[8], const float gb[8]){
  #pragma unroll
  for (int i = 0; i < 3; i++){
    const int row = rr[i];
    char* p = xb + row*256 + ((llo*16) ^ ((row&7)<<4));
    ushort8 u = __builtin_bit_cast(ushort8, *(const uint32x4*)p);
    float f[8]; float s = 0.f, ss = 0.f;
    #pragma unroll
    for (int j = 0; j < 8; j++){ f[j] = bf2f(u[j]); s += f[j]; ss += f[j]*f[j]; }
    #pragma unroll
    for (int m = 1; m < 16; m <<= 1){ s += __shfl_xor(s, m); ss += __shfl_xor(ss, m); }
    const float mean = s*(1.f/128.f);
    const float var  = ss*(1.f/128.f) - mean*mean;
    const float rstd = rsqrtf(var + 1e-5f);
    #pragma unroll
    for (int j = 0; j < 8; j++){
      const float g = fmaxf((f[j]-mean)*rstd*gw[j] + gb[j], 0.f);
      u[j] = f2bf(g);
    }
    *(uint32x4*)p = __builtin_bit_cast(uint32x4, u);
  }
}

// ======================= k_edge_mfma (unchanged from R2) =======================
#define NITER ((NE + 95) / 96)

__global__ __launch_bounds__(512, 2) void k_edge_mfma(
    const float* __restrict__ agt_ctrs, const float* __restrict__ ctx_ctrs,
    const int* __restrict__ hi, const int* __restrict__ wi,
    const float* __restrict__ dist_w1, const float* __restrict__ dist_b1,
    const float* __restrict__ dist_gw, const float* __restrict__ dist_gb,
    const float* __restrict__ ctx_gw, const float* __restrict__ ctx_gb,
    const float* __restrict__ dist_w2, const float* __restrict__ ctx_w1,
    const float* __restrict__ ctx_w2,
    const uint16_t* __restrict__ QW, const uint16_t* __restrict__ CtxP,
    float* __restrict__ A0){
  extern __shared__ __align__(16) char smem[];
  const int tid  = threadIdx.x;
  const int wave = tid >> 6, lane = tid & 63;
  const int grp  = wave >> 2, wv = wave & 3;
  const int lhi  = lane >> 4, llo = lane & 15;

  stage_wsz(smem,         dist_w2, 128, 0, tid);
  stage_wsz(smem + 32768, ctx_w1,  384, 0, tid);
  stage_wsz(smem + 65536, ctx_w2,  128, 0, tid);

  char* xb = smem + 98304 + grp*12288;
  int*  hb = (int*)(smem + 122880) + grp*96;

  const int c0 = llo*8;
  float w1x[8], w1y[8], b1v[8], dgw[8], dgb[8], cgw[8], cgb[8];
  #pragma unroll
  for (int j = 0; j < 8; j++){
    w1x[j] = dist_w1[(c0+j)*2 + 0];
    w1y[j] = dist_w1[(c0+j)*2 + 1];
    b1v[j] = dist_b1[c0+j];
    dgw[j] = dist_gw[c0+j]; dgb[j] = dist_gb[c0+j];
    cgw[j] = ctx_gw[c0+j];  cgb[j] = ctx_gb[c0+j];
  }
  __syncthreads();

  for (int it = blockIdx.x; it < NITER; it += gridDim.x){
    const long ebase = (long)it*96 + grp*48;
    if (wv == 0 && lane < 48){
      const long e = ebase + lane;
      int h = 0, w = 0;
      if (e < NE){ h = hi[e]; w = wi[e]; }
      hb[lane] = h; hb[48 + lane] = w;
    }
    __syncthreads();
    int rr[3], rh[3], rw[3];
    ushort8 qg[3], cg[3];
    float2 acs[3], ccs[3];
    #pragma unroll
    for (int i = 0; i < 3; i++){
      rr[i] = wv*12 + i*4 + lhi;
      rh[i] = hb[rr[i]]; rw[i] = hb[48 + rr[i]];
      qg[i]  = *(const ushort8*)&QW  [(size_t)rh[i]*D + c0];
      cg[i]  = *(const ushort8*)&CtxP[(size_t)rw[i]*D + c0];
      acs[i] = *(const float2*)&agt_ctrs[(size_t)rh[i]*2];
      ccs[i] = *(const float2*)&ctx_ctrs[(size_t)rw[i]*2];
    }
    #pragma unroll
    for (int i = 0; i < 3; i++){
      const float dx = acs[i].x - ccs[i].x, dy = acs[i].y - ccs[i].y;
      ushort8 u;
      #pragma unroll
      for (int j = 0; j < 8; j++)
        u[j] = f2bf(fmaxf(fmaf(dx, w1x[j], fmaf(dy, w1y[j], b1v[j])), 0.f));
      *(uint32x4*)(xb + rr[i]*256 + ((llo*16) ^ ((rr[i]&7)<<4))) =
          __builtin_bit_cast(uint32x4, u);
    }
    __syncthreads();
    f32x4 acc1[3][2];
    #pragma unroll
    for (int mt = 0; mt < 3; mt++){ acc1[mt][0] = (f32x4)0.f; acc1[mt][1] = (f32x4)0.f; }
    mm_stage(xb, smem, wv, llo, lhi, acc1);
    __syncthreads();
    #pragma unroll
    for (int i = 0; i < 3; i++){
      ushort8 u;
      #pragma unroll
      for (int j = 0; j < 8; j++) u[j] = f2bf(bf2f(qg[i][j]) + bf2f(cg[i][j]));
      *(uint32x4*)(xb + rr[i]*256 + ((llo*16) ^ ((rr[i]&7)<<4))) =
          __builtin_bit_cast(uint32x4, u);
    }
    __syncthreads();
    f32x4 acc2[3][2];
    #pragma unroll
    for (int mt = 0; mt < 3; mt++)
      #pragma unroll
      for (int ntl = 0; ntl < 2; ntl++)
        #pragma unroll
        for (int r = 0; r < 4; r++){
          const int m = mt*16 + lhi*4 + r;
          const int n = wv*32 + ntl*16 + llo;
          acc2[mt][ntl][r] = bf2f(*(const uint16_t*)(xb + m*256 + ((n*2) ^ ((m&7)<<4))));
        }
    __syncthreads();
    scat_acc(xb, acc1, wv, llo, lhi);
    __syncthreads();
    gn_rowpass(xb, rr, llo, dgw, dgb);
    __syncthreads();
    mm_stage(xb, smem + 32768, wv, llo, lhi, acc2);
    __syncthreads();
    scat_acc(xb, acc2, wv, llo, lhi);
    __syncthreads();
    gn_rowpass(xb, rr, llo, cgw, cgb);
    __syncthreads();
    f32x4 acc3[3][2];
    #pragma unroll
    for (int mt = 0; mt < 3; mt++){ acc3[mt][0] = (f32x4)0.f; acc3[mt][1] = (f32x4)0.f; }
    mm_stage(xb, smem + 65536, wv, llo, lhi, acc3);
    #pragma unroll
    for (int mt = 0; mt < 3; mt++)
      #pragma unroll
      for (int ntl = 0; ntl < 2; ntl++)
        #pragma unroll
        for (int r = 0; r < 4; r++){
          const int m = mt*16 + lhi*4 + r;
          if (ebase + m < NE){
            const int n = wv*32 + ntl*16 + llo;
            atomicAdd(&A0[(size_t)hb[m]*D + n], acc3[mt][ntl][r]);
          }
        }
    __syncthreads();
  }
}

// ======================= k_agent_pre_mfma =======================
// LDS: [0) wq 32768 | [32768) wa 32768 | [65536) w1q 32768 | [98304) xb 2x12288
#define NITER_A ((N_AGT + 95) / 96)

__global__ __launch_bounds__(512, 2) void k_agent_pre_mfma(
    const float* __restrict__ agts, const float* __restrict__ q_w,
    const float* __restrict__ ctx_w1, const float* __restrict__ agt_w,
    const float* __restrict__ q_gw, const float* __restrict__ q_gb,
    uint16_t* __restrict__ QW, float* __restrict__ A0){
  extern __shared__ __align__(16) char smem[];
  const int tid  = threadIdx.x;
  const int wave = tid >> 6, lane = tid & 63;
  const int grp  = wave >> 2, wv = wave & 3;
  const int lhi  = lane >> 4, llo = lane & 15;

  stage_wsz(smem,         q_w,    128, 0,   tid);
  stage_wsz(smem + 32768, agt_w,  128, 0,   tid);
  stage_wsz(smem + 65536, ctx_w1, 384, 128, tid);

  char* xb = smem + 98304 + grp*12288;
  const int c0 = llo*8;
  float qgw[8], qgb[8];
  #pragma unroll
  for (int j = 0; j < 8; j++){ qgw[j] = q_gw[c0+j]; qgb[j] = q_gb[c0+j]; }
  __syncthreads();

  const int tg = tid & 255;
  int rr[3];
  #pragma unroll
  for (int i = 0; i < 3; i++) rr[i] = wv*12 + i*4 + lhi;

  for (int it = blockIdx.x; it < NITER_A; it += gridDim.x){
    const int rbase = it*96 + grp*48;
    // stage agts tile f32 -> swizzled bf16
    for (int idx = tg; idx < 48*32; idx += 256){
      const int row = idx >> 5, c4 = idx & 31;
      int gr = rbase + row; if (gr >= N_AGT) gr = N_AGT - 1;
      const float4 f = *(const float4*)(agts + (size_t)gr*D + c4*4);
      const uint32_t lo = ((uint32_t)f2bf(f.y) << 16) | (uint32_t)f2bf(f.x);
      const uint32_t hi2 = ((uint32_t)f2bf(f.w) << 16) | (uint32_t)f2bf(f.z);
      *(uint2*)(xb + row*256 + ((c4*8) ^ ((row&7)<<4))) = make_uint2(lo, hi2);
    }
    __syncthreads();
    // A0 = agts @ agt_w^T  (direct f32 store)
    f32x4 acc[3][2];
    #pragma unroll
    for (int mt = 0; mt < 3; mt++){ acc[mt][0] = (f32x4)0.f; acc[mt][1] = (f32x4)0.f; }
    mm_stage(xb, smem + 32768, wv, llo, lhi, acc);
    #pragma unroll
    for (int mt = 0; mt < 3; mt++)
      #pragma unroll
      for (int ntl = 0; ntl < 2; ntl++)
        #pragma unroll
        for (int r = 0; r < 4; r++){
          const int m = mt*16 + lhi*4 + r;
          if (rbase + m < N_AGT){
            const int n = wv*32 + ntl*16 + llo;
            A0[(size_t)(rbase + m)*D + n] = acc[mt][ntl][r];
          }
        }
    // q_raw = agts @ q_w^T
    #pragma unroll
    for (int mt = 0; mt < 3; mt++){ acc[mt][0] = (f32x4)0.f; acc[mt][1] = (f32x4)0.f; }
    mm_stage(xb, smem, wv, llo, lhi, acc);
    __syncthreads();            // agts tile consumed by both matmuls
    scat_acc(xb, acc, wv, llo, lhi);
    __syncthreads();
    gn_rowpass(xb, rr, llo, qgw, qgb);   // xb = q = relu(gn(q_raw))
    __syncthreads();
    #pragma unroll
    for (int mt = 0; mt < 3; mt++){ acc[mt][0] = (f32x4)0.f; acc[mt][1] = (f32x4)0.f; }
    mm_stage(xb, smem + 65536, wv, llo, lhi, acc);
    __syncthreads();            // q consumed
    scat_acc(xb, acc, wv, llo, lhi);
    __syncthreads();
    // store QW rows (LDS-transposed, 16B per lane)
    #pragma unroll
    for (int i = 0; i < 3; i++){
      const int row = rr[i], gr = rbase + row;
      if (gr < N_AGT){
        const uint32x4 u = *(const uint32x4*)(xb + row*256 + ((llo*16) ^ ((row&7)<<4)));
        *(uint32x4*)(QW + (size_t)gr*D + c0) = u;
      }
    }
    __syncthreads();
  }
}

// ======================= k_post_mfma =======================
// LDS: [0) lin_w 32768 | [32768) xb 2x12288  = 57344 B
__global__ __launch_bounds__(512, 4) void k_post_mfma(
    float* __restrict__ A0, const float* __restrict__ agts,
    const float* __restrict__ lin_w,
    const float* __restrict__ norm_gw, const float* __restrict__ norm_gb,
    const float* __restrict__ lin_gw, const float* __restrict__ lin_gb){
  extern __shared__ __align__(16) char smem[];
  const int tid  = threadIdx.x;
  const int wave = tid >> 6, lane = tid & 63;
  const int grp  = wave >> 2, wv = wave & 3;
  const int lhi  = lane >> 4, llo = lane & 15;

  stage_wsz(smem, lin_w, 128, 0, tid);
  char* xb = smem + 32768 + grp*12288;
  const int c0 = llo*8;
  float ngw[8], ngb[8], lgw[8], lgb[8];
  #pragma unroll
  for (int j = 0; j < 8; j++){
    ngw[j] = norm_gw[c0+j]; ngb[j] = norm_gb[c0+j];
    lgw[j] = lin_gw[c0+j];  lgb[j] = lin_gb[c0+j];
  }
  __syncthreads();

  int rr[3];
  #pragma unroll
  for (int i = 0; i < 3; i++) rr[i] = wv*12 + i*4 + lhi;

  for (int it = blockIdx.x; it < NITER_A; it += gridDim.x){
    const int rbase = it*96 + grp*48;
    // phase 1: load A0 rows, GN1+relu in registers, store bf16 tile
    #pragma unroll
    for (int i = 0; i < 3; i++){
      const int row = rr[i];
      int gr = rbase + row; if (gr >= N_AGT) gr = N_AGT - 1;
      const float4 a0 = *(const float4*)(A0 + (size_t)gr*D + c0);
      const float4 a1 = *(const float4*)(A0 + (size_t)gr*D + c0 + 4);
      float f[8] = {a0.x,a0.y,a0.z,a0.w,a1.x,a1.y,a1.z,a1.w};
      float s = 0.f, ss = 0.f;
      #pragma unroll
      for (int j = 0; j < 8; j++){ s += f[j]; ss += f[j]*f[j]; }
      #pragma unroll
      for (int m = 1; m < 16; m <<= 1){ s += __shfl_xor(s, m); ss += __shfl_xor(ss, m); }
      const float mean = s*(1.f/128.f);
      const float var  = ss*(1.f/128.f) - mean*mean;
      const float rstd = rsqrtf(var + 1e-5f);
      ushort8 u;
      #pragma unroll
      for (int j = 0; j < 8; j++)
        u[j] = f2bf(fmaxf((f[j]-mean)*rstd*ngw[j] + ngb[j], 0.f));
      *(uint32x4*)(xb + row*256 + ((llo*16) ^ ((row&7)<<4))) =
          __builtin_bit_cast(uint32x4, u);
    }
    __syncthreads();
    f32x4 acc[3][2];
    #pragma unroll
    for (int mt = 0; mt < 3; mt++){ acc[mt][0] = (f32x4)0.f; acc[mt][1] = (f32x4)0.f; }
    mm_stage(xb, smem, wv, llo, lhi, acc);
    __syncthreads();
    scat_acc(xb, acc, wv, llo, lhi);
    __syncthreads();
    // phase 2: GN2 + residual + relu + f32 store
    #pragma unroll
    for (int i = 0; i < 3; i++){
      const int row = rr[i];
      const char* p = xb + row*256 + ((llo*16) ^ ((row&7)<<4));
      const ushort8 u = __builtin_bit_cast(ushort8, *(const uint32x4*)p);
      float f[8]; float s = 0.f, ss = 0.f;
      #pragma unroll
      for (int j = 0; j < 8; j++){ f[j] = bf2f(u[j]); s += f[j]; ss += f[j]*f[j]; }
      #pragma unroll
      for (int m = 1; m < 16; m <<= 1){ s += __shfl_xor(s, m); ss += __shfl_xor(ss, m); }
      const float mean = s*(1.f/128.f);
      const float var  = ss*(1.f/128.f) - mean*mean;
      const float rstd = rsqrtf(var + 1e-5f);
      const int gr = rbase + row;
      if (gr < N_AGT){
        const float4 r0 = *(const float4*)(agts + (size_t)gr*D + c0);
        const float4 r1 = *(const float4*)(agts + (size_t)gr*D + c0 + 4);
        const float res[8] = {r0.x,r0.y,r0.z,r0.w,r1.x,r1.y,r1.z,r1.w};
        float4 o0, o1;
        float o[8];
        #pragma unroll
        for (int j = 0; j < 8; j++)
          o[j] = fmaxf((f[j]-mean)*rstd*lgw[j] + lgb[j] + res[j], 0.f);
        o0.x=o[0]; o0.y=o[1]; o0.z=o[2]; o0.w=o[3];
        o1.x=o[4]; o1.y=o[5]; o1.z=o[6]; o1.w=o[7];
        *(float4*)(A0 + (size_t)gr*D + c0)     = o0;
        *(float4*)(A0 + (size_t)gr*D + c0 + 4) = o1;
      }
    }
    __syncthreads();
  }
}

// ======================= k_ctx (unchanged VALU) =======================
__device__ __forceinline__ void stage_w4(uint32_t* wp, const float* __restrict__ W,
                                         int rs, int co, int tid, int nthr){
  for (int idx = tid; idx < 32*128; idx += nthr){
    int p2 = idx & 31, o = idx >> 5;
    const float4 f = *(const float4*)(W + (size_t)o*rs + co + p2*4);
    uint32_t lo = ((uint32_t)f2bf(f.y) << 16) | (uint32_t)f2bf(f.x);
    uint32_t hi = ((uint32_t)f2bf(f.w) << 16) | (uint32_t)f2bf(f.z);
    *(uint2*)&wp[(p2*128 + o)*2] = make_uint2(lo, hi);
  }
}

__device__ __forceinline__ float dot128(const uint32_t* wp, const float* xb, int o){
  float acc = 0.f;
  #pragma unroll 8
  for (int p2 = 0; p2 < 32; p2++){
    const uint2 w = *(const uint2*)&wp[(p2*128 + o)*2];
    const float4 x = *(const float4*)&xb[p2*4];
    acc += x.x*bf_lo(w.x) + x.y*bf_hi(w.x) + x.z*bf_lo(w.y) + x.w*bf_hi(w.y);
  }
  return acc;
}

__global__ __launch_bounds__(128) void k_ctx(const float* __restrict__ ctx,
                                             const float* __restrict__ ctx_w1,
                                             uint16_t* __restrict__ CtxP){
  __shared__ __align__(16) uint32_t wc[32*128*2];
  __shared__ __align__(16) float xbuf[128];
  const int tid = threadIdx.x;
  stage_w4(wc, ctx_w1, 384, 256, tid, 128);
  __syncthreads();
  for (int row = blockIdx.x; row < N_CTX; row += gridDim.x){
    __syncthreads();
    xbuf[tid] = ctx[(size_t)row*D + tid];
    __syncthreads();
    const float acc = dot128(wc, xbuf, tid);
    CtxP[(size_t)row*D + tid] = f2bf(acc);
  }
}

extern "C" void kernel_launch(void* const* d_in, const int* in_sizes, int n_in,
                              void* d_out, int out_size, void* d_ws, size_t ws_size,
                              hipStream_t stream){
  const float* agts     = (const float*)d_in[0];
  const float* ctx      = (const float*)d_in[1];
  const float* agt_ctrs = (const float*)d_in[2];
  const float* ctx_ctrs = (const float*)d_in[3];
  const int*   hi       = (const int*)d_in[4];
  const int*   wi       = (const int*)d_in[5];
  const float* dist_w1  = (const float*)d_in[6];
  const float* dist_b1  = (const float*)d_in[7];
  const float* dist_w2  = (const float*)d_in[8];
  const float* dist_gw  = (const float*)d_in[9];
  const float* dist_gb  = (const float*)d_in[10];
  const float* q_w      = (const float*)d_in[11];
  const float* q_gw     = (const float*)d_in[12];
  const float* q_gb     = (const float*)d_in[13];
  const float* ctx_w1   = (const float*)d_in[14];
  const float* ctx_gw   = (const float*)d_in[15];
  const float* ctx_gb   = (const float*)d_in[16];
  const float* ctx_w2   = (const float*)d_in[17];
  const float* agt_w    = (const float*)d_in[18];
  const float* norm_gw  = (const float*)d_in[19];
  const float* norm_gb  = (const float*)d_in[20];
  const float* lin_w    = (const float*)d_in[21];
  const float* lin_gw   = (const float*)d_in[22];
  const float* lin_gb   = (const float*)d_in[23];

  uint16_t* QW   = (uint16_t*)d_ws;                 // 100000*128 bf16 = 25.6 MB
  uint16_t* CtxP = QW + (size_t)N_AGT * D;          // +2.56 MB
  float*    A0   = (float*)d_out;                   // accumulator lives in d_out

  const int EDGE_LDS = 123648;
  const int APRE_LDS = 122880;
  const int POST_LDS = 57344;
  hipFuncSetAttribute((const void*)k_edge_mfma,
                      hipFuncAttributeMaxDynamicSharedMemorySize, EDGE_LDS);
  hipFuncSetAttribute((const void*)k_agent_pre_mfma,
                      hipFuncAttributeMaxDynamicSharedMemorySize, APRE_LDS);
  hipFuncSetAttribute((const void*)k_post_mfma,
                      hipFuncAttributeMaxDynamicSharedMemorySize, POST_LDS);

  k_ctx<<<1024, 128, 0, stream>>>(ctx, ctx_w1, CtxP);
  k_agent_pre_mfma<<<256, 512, APRE_LDS, stream>>>(agts, q_w, ctx_w1, agt_w,
      q_gw, q_gb, QW, A0);
  k_edge_mfma<<<256, 512, EDGE_LDS, stream>>>(agt_ctrs, ctx_ctrs, hi, wi,
      dist_w1, dist_b1, dist_gw, dist_gb, ctx_gw, ctx_gb,
      dist_w2, ctx_w1, ctx_w2, QW, CtxP, A0);
  k_post_mfma<<<512, 512, POST_LDS, stream>>>(A0, agts, lin_w,
      norm_gw, norm_gb, lin_gw, lin_gb);
}